// Round 13
// baseline (1010.611 us; speedup 1.0000x reference)
//
#include <hip/hip_runtime.h>
#include <math.h>

#define HH 64
#define WW 64
#define NIMG 4
#define CIN 512
#define AA 9
#define HWA (HH*WW*AA)          // 36864
#define PRE_NMS 6000
#define POST_NMS 300
#define NEGV (-1e10f)
#define NEGK 0xD01502F9u        // descending-order key of -1e10f
#define NWORD 94                // ceil(6000/64)

#define OFF1 589824             // rpn_scores
#define OFF2 884736             // rois
#define OFF3 889536             // roi_indices
#define OFF4 890736             // anchors

typedef unsigned int u32;
typedef unsigned long long u64;
typedef _Float16 f16;
typedef _Float16 half8 __attribute__((ext_vector_type(8)));
typedef float f32x4 __attribute__((ext_vector_type(4)));

struct AnchBase { float v[36]; };   // host-computed f64->f32 anchor base (4 per a)

__device__ __forceinline__ void gload_lds16(const void* g, void* l)
{
    __builtin_amdgcn_global_load_lds((const __attribute__((address_space(1))) void*)g,
                                     (__attribute__((address_space(3))) void*)l,
                                     16, 0, 0);
}

// ---------------- prep: x[n][ci][y][xc] f32 -> x_t[n][y][xc][ci] fp16 hi/lo ----------
__global__ __launch_bounds__(256) void k_prep_x(const float* __restrict__ x,
                                                f16* __restrict__ xh,
                                                f16* __restrict__ xl)
{
    __shared__ float tile[64][65];
    int ci0 = blockIdx.x * 64, y = blockIdx.y, n = blockIdx.z;
    int t = threadIdx.x;
    #pragma unroll
    for (int l = 0; l < 16; ++l) {
        int idx = l * 256 + t;
        int cc = idx >> 6, xc = idx & 63;
        tile[cc][xc] = x[((size_t)(n * CIN + ci0 + cc) * HH + y) * WW + xc];
    }
    __syncthreads();
    #pragma unroll
    for (int l = 0; l < 16; ++l) {
        int idx = l * 256 + t;
        int xc = idx >> 6, cc = idx & 63;
        float v = tile[cc][xc];
        f16 hi = (f16)v;
        f16 lo = (f16)(v - (float)hi);
        size_t o = ((size_t)(n * 64 + y) * 64 + xc) * 512 + ci0 + cc;
        xh[o] = hi; xl[o] = lo;
    }
}

// ---------------- prep: W1[co][ci][tap] f32 -> W2[tap][co][ci] fp16 hi/lo ----------
__global__ __launch_bounds__(256) void k_prep_w(const float* __restrict__ W1,
                                                f16* __restrict__ wh,
                                                f16* __restrict__ wl)
{
    int idx = blockIdx.x * 256 + threadIdx.x;   // 512*512
    int co = idx >> 9, ci = idx & 511;
    #pragma unroll
    for (int tap = 0; tap < 9; ++tap) {
        float v = W1[(size_t)idx * 9 + tap];
        f16 hi = (f16)v;
        f16 lo = (f16)(v - (float)hi);
        size_t o = ((size_t)tap * 512 + co) * 512 + ci;
        wh[o] = hi; wl[o] = lo;
    }
}

// ---------------- conv3x3 via MFMA fp16x3 implicit GEMM ----------------------------
// R13 (single change): tile 64co x 64px x 1y, grid 2048 (was 2y/1024). The old grid
// was EXACTLY 4 blocks/CU — occupancy was grid-limited, which is why all schedule
// variants plateaued at ~320us / 45% occupancy. LDS drops to [2][3][66][32]=25344B
// -> 6 blocks resident (24 waves/CU) to hide the single-buffer barrier drains.
// Same padded-column layout, swizzles, and per-output MFMA stream (bit-identical).
__global__ __launch_bounds__(256, 4) void k_conv_mfma(const f16* __restrict__ xh,
                                                      const f16* __restrict__ xl,
                                                      const f16* __restrict__ wh,
                                                      const f16* __restrict__ wl,
                                                      const float* __restrict__ bias,
                                                      float* __restrict__ mid)
{
    __shared__ f16 sX[2][3][66][32];   // [plane][row y0-1..y0+1][col 0..65][ci] = 25344 B
    const int t = threadIdx.x;
    const int lid = blockIdx.x + 8 * (blockIdx.y + 64 * blockIdx.z);   // launched id
    const int logical = (lid & 7) * 256 + (lid >> 3);                  // bijective
    const int co0 = (logical & 7) * 64;
    const int g = logical >> 3;        // 0..255 = yb + 64*n
    const int yb = g & 63, n = g >> 6;
    const int y0 = yb;
    const int wv = t >> 6, lane = t & 63;
    const int q = lane >> 4, li = lane & 15;
    const int mh = wv & 1;             // co half (32 co)
    const int xhp = wv >> 1;           // px half (32 px)

    // u32 strides: plane 3168, row 1056, col 16
    {   // zero pad columns (cols 0 and 65) of all 6 plane-rows: 192 u32 total
        if (t < 192) {
            int pr = t >> 5, j = t & 31;
            int col = (j < 16) ? 0 : 65, e = j & 15;
            u32* p = (u32*)&sX[0][0][0][0];
            p[(pr / 3) * 3168 + (pr % 3) * 1056 + col * 16 + e] = 0;
        }
    }
    if (yb == 0 || yb == 63) {         // zero vertical-halo row (both planes)
        int r = (yb == 0) ? 0 : 2;
        u32* p = (u32*)&sX[0][0][0][0];
        #pragma unroll
        for (int l = 0; l < 9; ++l) {
            int idx = l * 256 + t;     // 0..2111 used
            if (idx < 2112) {
                int plane = (idx >= 1056) ? 1 : 0;
                int rr = idx - plane * 1056;
                p[plane * 3168 + r * 1056 + rr] = 0;
            }
        }
    }

    f32x4 acc[2][2];   // [mt][xn]
    #pragma unroll
    for (int mt = 0; mt < 2; ++mt)
        #pragma unroll
        for (int xn = 0; xn < 2; ++xn)
            acc[mt][xn] = (f32x4){0.f, 0.f, 0.f, 0.f};

    // staging: 24 wave-insts x 1 KB (6 per wave); LDS col g+1 <- global col g,
    // slot s_l receives global ci-slot s_l ^ ((g>>1)&3) via pre-swizzled source.
    auto prefetch = [&](int ci0) {
        #pragma unroll
        for (int m = 0; m < 6; ++m) {
            int k2 = wv * 6 + m;               // 0..23, wave-uniform
            int plane = k2 / 12;
            int rem = k2 - plane * 12;
            int row = rem >> 2;                // 0..2
            int gy = y0 - 1 + row;
            if ((unsigned)gy < 64u) {
                int col = ((rem & 3) << 4) + (lane >> 2);
                int s = (lane & 3) ^ ((lane >> 3) & 3);   // pre-swizzled global slot
                const f16* src = (plane ? xl : xh) +
                    (((size_t)(n * 64 + gy) * 64 + col) * 512 + ci0 + s * 8);
                f16* dst = &sX[0][0][0][0] + (size_t)plane * 6336 + row * 2112
                           + (1 + (rem & 3) * 16) * 32 + lane * 8;
                gload_lds16(src, dst);
            }
        }
    };

    const size_t wb0 = (size_t)(co0 + mh * 32 + li) * 512 + q * 8;
    const f16* pWh = wh + wb0;
    const f16* pWl = wl + wb0;
    half8 wa[2][2], wn[2][2];
    auto loadW = [&](half8 (&w)[2][2], int ci0, int tap) {
        #pragma unroll
        for (int mt = 0; mt < 2; ++mt) {
            size_t off = (size_t)tap * 262144 + (size_t)mt * 8192 + ci0;
            w[0][mt] = *(const half8*)(pWh + off);
            w[1][mt] = *(const half8*)(pWl + off);
        }
    };

    // loop-invariant B-read pointers: LDS col lc = xc + kx (0..65); global g = lc-1.
    const f16* pB[2][3];
    #pragma unroll
    for (int xn = 0; xn < 2; ++xn)
        #pragma unroll
        for (int kx = 0; kx < 3; ++kx) {
            int lc = xhp * 32 + xn * 16 + li + kx;
            int qe = q ^ (((lc - 1) >> 1) & 3);
            pB[xn][kx] = &sX[0][0][0][0] + lc * 32 + qe * 8;
        }

    auto loadB = [&](half8 (&Bf)[2][2], int tap) {
        const int ky = tap / 3, kx = tap - ky * 3;
        #pragma unroll
        for (int xn = 0; xn < 2; ++xn) {
            const f16* ph = pB[xn][kx] + ky * 2112;      // row stride 66*32 f16
            Bf[0][xn] = *(const half8*)ph;
            Bf[1][xn] = *(const half8*)(ph + 6336);      // plane stride f16
        }
    };

    prefetch(0);
    loadW(wa, 0, 0);

    for (int chunk = 0; chunk < 16; ++chunk) {
        const int ci0 = chunk * 32;
        __syncthreads();

        half8 B0[2][2], Bn[2][2];      // [plane][xn]
        loadB(B0, 0);

        #pragma unroll
        for (int tap = 0; tap < 9; ++tap) {
            if (tap < 8) {
                loadW(wn, ci0, tap + 1);
                loadB(Bn, tap + 1);
            }
            #pragma unroll
            for (int mt = 0; mt < 2; ++mt)
                #pragma unroll
                for (int xn = 0; xn < 2; ++xn)
                    acc[mt][xn] = __builtin_amdgcn_mfma_f32_16x16x32_f16(wa[0][mt], B0[0][xn], acc[mt][xn], 0, 0, 0);
            #pragma unroll
            for (int mt = 0; mt < 2; ++mt)
                #pragma unroll
                for (int xn = 0; xn < 2; ++xn)
                    acc[mt][xn] = __builtin_amdgcn_mfma_f32_16x16x32_f16(wa[0][mt], B0[1][xn], acc[mt][xn], 0, 0, 0);
            #pragma unroll
            for (int mt = 0; mt < 2; ++mt)
                #pragma unroll
                for (int xn = 0; xn < 2; ++xn)
                    acc[mt][xn] = __builtin_amdgcn_mfma_f32_16x16x32_f16(wa[1][mt], B0[0][xn], acc[mt][xn], 0, 0, 0);

            if (tap < 8) {
                #pragma unroll
                for (int pl = 0; pl < 2; ++pl)
                    #pragma unroll
                    for (int mt = 0; mt < 2; ++mt) wa[pl][mt] = wn[pl][mt];
                #pragma unroll
                for (int pl = 0; pl < 2; ++pl)
                    #pragma unroll
                    for (int xn = 0; xn < 2; ++xn) B0[pl][xn] = Bn[pl][xn];
            }
        }

        if (chunk + 1 < 16) {
            __syncthreads();
            prefetch(ci0 + 32);
            loadW(wa, ci0 + 32, 0);
        }
    }

    // epilogue: D row=q*4+r -> co, col=li -> px; bias + relu (single y row)
    #pragma unroll
    for (int mt = 0; mt < 2; ++mt) {
        #pragma unroll
        for (int r = 0; r < 4; ++r) {
            int co = co0 + mh * 32 + mt * 16 + q * 4 + r;
            float bv = bias[co];
            #pragma unroll
            for (int xn = 0; xn < 2; ++xn) {
                int xc = xhp * 32 + xn * 16 + li;
                float v = acc[mt][xn][r] + bv;
                mid[((size_t)(n * 512 + co) * HH + y0) * WW + xc] = v > 0.f ? v : 0.f;
            }
        }
    }
}

// ---------------- head weights -> [ci][co] (co: 0..17 score, 18..53 loc, pad 64) ----
__global__ __launch_bounds__(256) void k_htrans(const float* __restrict__ Ws,
                                                const float* __restrict__ Wl,
                                                float* __restrict__ Wt2)
{
    int i = blockIdx.x * 256 + threadIdx.x;   // 512*64
    if (i >= 512 * 64) return;
    int ci = i >> 6, co = i & 63;
    float v = 0.f;
    if (co < 18) v = Ws[co * 512 + ci];
    else if (co < 54) v = Wl[(co - 18) * 512 + ci];
    Wt2[i] = v;
}

// ---------------- 1x1 heads as GEMM: sraw[n][co64][px4096] ----------------
__global__ __launch_bounds__(256) void k_hgemm(const float* __restrict__ mid,
                                               const float* __restrict__ Wt2,
                                               float* __restrict__ sraw)
{
    __shared__ float sM[32][64];   // [ci][px]
    __shared__ float sW2[32][64];  // [ci][co]
    const int t = threadIdx.x;
    const int px0 = blockIdx.x * 64, n = blockIdx.y;
    const int tx = t & 15, ty = t >> 4;

    float acc[4][4];
    #pragma unroll
    for (int c = 0; c < 4; ++c)
        #pragma unroll
        for (int j = 0; j < 4; ++j) acc[c][j] = 0.f;

    for (int ci0 = 0; ci0 < 512; ci0 += 32) {
        __syncthreads();
        #pragma unroll
        for (int l = 0; l < 8; ++l) {
            int i = l * 256 + t;
            int ci = i >> 6, px = i & 63;
            sM[ci][px] = mid[((size_t)n * 512 + ci0 + ci) * 4096 + px0 + px];
            sW2[ci][px] = Wt2[(size_t)(ci0 + ci) * 64 + px];
        }
        __syncthreads();
        #pragma unroll
        for (int ci = 0; ci < 32; ++ci) {
            float mv[4], wv[4];
            #pragma unroll
            for (int j = 0; j < 4; ++j) mv[j] = sM[ci][tx * 4 + j];
            #pragma unroll
            for (int c = 0; c < 4; ++c) wv[c] = sW2[ci][ty * 4 + c];
            #pragma unroll
            for (int c = 0; c < 4; ++c)
                #pragma unroll
                for (int j = 0; j < 4; ++j) acc[c][j] += wv[c] * mv[j];
        }
    }
    #pragma unroll
    for (int c = 0; c < 4; ++c) {
        float4 v = make_float4(acc[c][0], acc[c][1], acc[c][2], acc[c][3]);
        *(float4*)&sraw[((size_t)n * 64 + ty * 4 + c) * 4096 + px0 + tx * 4] = v;
    }
}

// ---------------- decode: softmax, loc2bbox, clip, keys, head outputs ----------------
__global__ __launch_bounds__(256) void k_decode(const float* __restrict__ sraw,
                                                const float* __restrict__ bsc,
                                                const float* __restrict__ blc,
                                                const int* __restrict__ ph,
                                                const int* __restrict__ pw,
                                                float* __restrict__ out,
                                                float* __restrict__ boxes,
                                                u32* __restrict__ key,
                                                AnchBase ab)
{
    int p = blockIdx.x * 256 + threadIdx.x;   // 0..16383
    int n = p >> 12, pi = p & 4095;
    int y = pi >> 6, xq = pi & 63;

    const float* S = sraw + (size_t)n * 64 * 4096 + pi;
    float* o0 = out + (size_t)n * 147456;
    float* o1 = out + OFF1 + (size_t)n * 73728;
    float IHf = (float)(*ph), IWf = (float)(*pw);

    #pragma unroll
    for (int a = 0; a < 9; ++a) {
        float s0 = S[(size_t)(2 * a) * 4096] + bsc[2 * a];
        float s1 = S[(size_t)(2 * a + 1) * 4096] + bsc[2 * a + 1];
        float dy = S[(size_t)(18 + 4 * a) * 4096] + blc[4 * a];
        float dx = S[(size_t)(19 + 4 * a) * 4096] + blc[4 * a + 1];
        float dh = S[(size_t)(20 + 4 * a) * 4096] + blc[4 * a + 2];
        float dw = S[(size_t)(21 + 4 * a) * 4096] + blc[4 * a + 3];

        o1[(pi * 9 + a) * 2 + 0] = s0;
        o1[(pi * 9 + a) * 2 + 1] = s1;
        o0[(pi * 9 + a) * 4 + 0] = dy;
        o0[(pi * 9 + a) * 4 + 1] = dx;
        o0[(pi * 9 + a) * 4 + 2] = dh;
        o0[(pi * 9 + a) * 4 + 3] = dw;

        // softmax fg (max-subtracted like jax.nn.softmax)
        float mm = fmaxf(s0, s1);
        float e0 = expf(s0 - mm), e1 = expf(s1 - mm);
        float fg = e1 / (e0 + e1);

        // anchor base from host-computed table (bit-identical to f64 path)
        float a0 = ab.v[4 * a + 0] + (float)(y * 16);
        float a1 = ab.v[4 * a + 1] + (float)(xq * 16);
        float a2 = ab.v[4 * a + 2] + (float)(y * 16);
        float a3 = ab.v[4 * a + 3] + (float)(xq * 16);

        // loc2bbox
        float h = a2 - a0, w = a3 - a1;
        float cy = a0 + 0.5f * h, cx = a1 + 0.5f * w;
        float ncy = dy * h + cy, ncx = dx * w + cx;
        float nh = expf(dh) * h, nw = expf(dw) * w;
        float b0 = fminf(fmaxf(ncy - 0.5f * nh, 0.f), IHf);
        float b1 = fminf(fmaxf(ncx - 0.5f * nw, 0.f), IWf);
        float b2 = fminf(fmaxf(ncy + 0.5f * nh, 0.f), IHf);
        float b3 = fminf(fmaxf(ncx + 0.5f * nw, 0.f), IWf);

        bool ok = (b2 - b0 >= 16.0f) && (b3 - b1 >= 16.0f);
        float sc = ok ? fg : NEGV;

        int gi = n * HWA + pi * 9 + a;
        ((float4*)boxes)[gi] = make_float4(b0, b1, b2, b3);
        u32 u = __float_as_uint(sc);
        u32 kasc = (u & 0x80000000u) ? ~u : (u | 0x80000000u);
        key[gi] = ~kasc;   // ascending key == descending score
    }
}

// ---------------- anchors out + roi_indices + zero rois ----------------
__global__ void k_misc(float* __restrict__ out, AnchBase ab)
{
    int i = blockIdx.x * 256 + threadIdx.x;
    if (i < 4800) out[OFF2 + i] = 0.f;
    if (i < 1200) out[OFF3 + i] = (float)(i / 300);
    if (i < HWA) {
        int pi = i / 9, a = i - pi * 9;
        int y = pi >> 6, xq = pi & 63;
        out[OFF4 + i * 4 + 0] = ab.v[4 * a + 0] + (float)(y * 16);
        out[OFF4 + i * 4 + 1] = ab.v[4 * a + 1] + (float)(xq * 16);
        out[OFF4 + i * 4 + 2] = ab.v[4 * a + 2] + (float)(y * 16);
        out[OFF4 + i * 4 + 3] = ab.v[4 * a + 3] + (float)(xq * 16);
    }
}

// ---------------- fused select(+compact)+sort: radix rank-6000 -> LDS bitonic -------
__global__ __launch_bounds__(1024) void k_selsort(const u32* __restrict__ key,
                                                  const float* __restrict__ boxes,
                                                  float* __restrict__ boxesS,
                                                  int* __restrict__ nvalid)
{
    __shared__ u64 sK[8192];   // 64 KiB
    __shared__ int hist[256];
    __shared__ u32 sPref;
    __shared__ int sR;
    __shared__ int cLess, cEq, cVal;
    int n = blockIdx.x, t = threadIdx.x;
    const u32* k0 = key + (size_t)n * HWA;

    u32 pref = 0, mask = 0;
    int R = PRE_NMS;
    for (int pass = 0; pass < 4; ++pass) {
        int shift = 24 - pass * 8;
        if (t < 256) hist[t] = 0;
        __syncthreads();
        for (int i = t; i < HWA; i += 1024) {
            u32 k = k0[i];
            if ((k & mask) == pref) atomicAdd(&hist[(k >> shift) & 255], 1);
        }
        __syncthreads();
        if (t == 0) {
            int cum = 0;
            for (int b = 0; b < 256; ++b) {
                int c = hist[b];
                if (cum + c >= R) { sPref = pref | ((u32)b << shift); sR = R - cum; break; }
                cum += c;
            }
        }
        __syncthreads();
        pref = sPref; R = sR; mask |= (0xFFu << shift);
        __syncthreads();
    }
    u32 T = pref;   // exact 6000th smallest key
    if (t == 0) { cLess = 0; cEq = 0; cVal = 0; }
    __syncthreads();
    for (int i = t; i < HWA; i += 1024) {
        u32 k = k0[i];
        if (k < NEGK) atomicAdd(&cVal, 1);
        if (k < T) {
            int p = atomicAdd(&cLess, 1);
            sK[p] = ((u64)k << 32) | (u32)i;
        } else if (k == T) {
            int p = atomicAdd(&cEq, 1);
            if (p < R) sK[PRE_NMS - 1 - p] = ((u64)k << 32) | (u32)i;
        }
    }
    for (int i = PRE_NMS + t; i < 8192; i += 1024) sK[i] = ~0ull;
    __syncthreads();
    if (t == 0) nvalid[n] = cVal < PRE_NMS ? cVal : PRE_NMS;

    // bitonic sort of 8192 in LDS
    for (unsigned k = 2; k <= 8192; k <<= 1) {
        for (unsigned j = k >> 1; j > 0; j >>= 1) {
            __syncthreads();
            #pragma unroll
            for (int v = 0; v < 8; ++v) {
                int i = v * 1024 + t;
                int ixj = i ^ (int)j;
                if (ixj > i) {
                    u64 a = sK[i], b = sK[ixj];
                    bool up = ((i & (int)k) == 0);
                    if (up ? (a > b) : (a < b)) { sK[i] = b; sK[ixj] = a; }
                }
            }
        }
    }
    __syncthreads();
    const float4* bsrc = (const float4*)boxes + (size_t)n * HWA;
    float4* bdst = (float4*)boxesS + (size_t)n * PRE_NMS;
    for (int i = t; i < PRE_NMS; i += 1024) {
        u32 idx = (u32)(sK[i] & 0xFFFFFFFFu);
        bdst[i] = bsrc[idx];
    }
}

// ---------------- IoU suppression bitmask, WORD-MAJOR: mask[n][w][i] ----------------
__global__ __launch_bounds__(64) void k_iou(const float* __restrict__ boxesS,
                                            u64* __restrict__ mask)
{
    __shared__ float4 cb[64];
    int w = blockIdx.x, ic = blockIdx.y, n = blockIdx.z;
    if (w < ic) return;                       // strictly-lower triangle: unused
    int t = threadIdx.x;
    const float4* B = (const float4*)boxesS + (size_t)n * PRE_NMS;
    int jc = w * 64 + t;
    cb[t] = (jc < PRE_NMS) ? B[jc] : make_float4(0.f, 0.f, 0.f, 0.f);
    __syncthreads();
    int i = ic * 64 + t;
    if (i >= PRE_NMS) return;
    float4 bb = B[i];
    float area1 = (bb.z - bb.x) * (bb.w - bb.y);
    u64 m = 0;
    #pragma unroll 8
    for (int j = 0; j < 64; ++j) {
        float4 o = cb[j];
        float ty_ = fmaxf(bb.x, o.x), tx_ = fmaxf(bb.y, o.y);
        float by_ = fminf(bb.z, o.z), bx_ = fminf(bb.w, o.w);
        float inter = fmaxf(by_ - ty_, 0.f) * fmaxf(bx_ - tx_, 0.f);
        float area2 = (o.z - o.x) * (o.w - o.y);
        float iou = inter / (area1 + area2 - inter + 1e-9f);
        if (iou > 0.7f) m |= (1ull << j);
    }
    mask[((size_t)n * NWORD + w) * PRE_NMS + i] = m;   // contiguous per block
}

// ---------------- greedy bitmask NMS: chunk-resolved, word-major mask ---------------
__global__ __launch_bounds__(64) void k_nms3(const u64* __restrict__ mask,
                                             const int* __restrict__ nvalid,
                                             const float* __restrict__ boxesS,
                                             float* __restrict__ rois)
{
    __shared__ u64 diag[NWORD * 128];   // per chunk: 64 used + 64 overread slack
    int n = blockIdx.x, lane = threadIdx.x;
    int nv = nvalid[n];
    const u64* M = mask + (size_t)n * NWORD * PRE_NMS;   // [w][i]
    const float4* B = (const float4*)boxesS + (size_t)n * PRE_NMS;

    auto vmask = [&](int w) -> u64 {
        int lo = w * 64;
        if (nv >= lo + 64) return ~0ull;
        if (nv <= lo) return 0ull;
        return (1ull << (nv - lo)) - 1ull;
    };
    u64 c0 = vmask(lane);                                      // words 0..63
    u64 c1 = (lane < NWORD - 64) ? vmask(64 + lane) : 0ull;    // words 64..93

    for (int c = 0; c < NWORD; ++c) {
        const char* src = (const char*)(M + (size_t)c * PRE_NMS + c * 64) + lane * 16;
        gload_lds16(src, &diag[(size_t)c * 128]);
    }
    asm volatile("s_waitcnt vmcnt(0)" ::: "memory");
    __builtin_amdgcn_sched_barrier(0);

    const u64* Mw0 = M + (size_t)lane * PRE_NMS;
    const u64* Mw1 = (lane < NWORD - 64) ? (M + (size_t)(64 + lane) * PRE_NMS) : M;

    int cnt = 0;
    for (int c = 0; c < NWORD; ++c) {
        u64 w = (c < 64) ? __shfl(c0, c) : __shfl(c1, c - 64);   // uniform word
        if (w == 0) continue;

        u64 dl = diag[(size_t)c * 128 + lane];

        u64 selw = 0;
        u64 ww = w;
        while (ww && cnt < POST_NMS) {
            int j = __builtin_ctzll(ww);
            int sel = c * 64 + j;
            if (lane == 0) {
                float4 bb = B[sel];
                float* orow = rois + (size_t)(n * POST_NMS + cnt) * 4;
                orow[0] = bb.x; orow[1] = bb.y; orow[2] = bb.z; orow[3] = bb.w;
            }
            cnt++;
            selw |= 1ull << j;
            u64 dj = __shfl(dl, j);          // row sel's word c (self-bit set)
            ww &= ~dj;
            ww &= ~(1ull << j);
        }
        if (cnt >= POST_NMS) break;

        u64 s = selw;
        while (s) {
            int ids[8];
            u64 r0v[8], r1v[8];
            #pragma unroll
            for (int z = 0; z < 8; ++z) {
                int idz = -1;
                if (s) { int j = __builtin_ctzll(s); s &= s - 1; idz = c * 64 + j; }
                ids[z] = idz;
            }
            #pragma unroll
            for (int z = 0; z < 8; ++z) {
                if (ids[z] >= 0) {
                    r0v[z] = Mw0[ids[z]];
                    r1v[z] = (lane < NWORD - 64) ? Mw1[ids[z]] : 0ull;
                } else { r0v[z] = 0ull; r1v[z] = 0ull; }
            }
            #pragma unroll
            for (int z = 0; z < 8; ++z) { c0 &= ~r0v[z]; c1 &= ~r1v[z]; }
        }
    }
}

extern "C" void kernel_launch(void* const* d_in, const int* in_sizes, int n_in,
                              void* d_out, int out_size, void* d_ws, size_t ws_size,
                              hipStream_t stream)
{
    const float* x  = (const float*)d_in[0];
    const float* W1 = (const float*)d_in[1];
    const float* b1 = (const float*)d_in[2];
    const float* Ws = (const float*)d_in[3];
    const float* bs = (const float*)d_in[4];
    const float* Wl = (const float*)d_in[5];
    const float* bl = (const float*)d_in[6];
    const int* ih   = (const int*)d_in[7];
    const int* iw   = (const int*)d_in[8];
    float* out = (float*)d_out;
    char* ws = (char*)d_ws;

    // during conv:
    f16*   Wh2    = (f16*)  (ws);                 //  4,718,592 B (dead after conv)
    f16*   Wl2    = (f16*)  (ws + 4718592);       //  4,718,592 B (dead after conv)
    float* mid    = (float*)(ws + 9437184);       // 33,554,432 B (dead after hgemm)
    f16*   xh     = (f16*)  (ws + 42991616);      // 16,777,216 B (dead after conv)
    f16*   xl     = (f16*)  (ws + 59768832);      // 16,777,216 B (dead after conv)
    // after conv (reusing xh region at identical old offsets):
    float* boxes  = (float*)(ws + 42991616);      //  2,359,296 B
    u32*   key    = (u32*)  (ws + 45350912);      //    589,824 B
    float* boxesS = (float*)(ws + 46202880);      //    384,000 B
    int*   nval   = (int*)  (ws + 46586880);      //         16 B
    // reuse dead Wh2 region after conv:
    float* Wt2    = (float*)(ws);                 //    131,072 B [ci][co64]
    float* sraw   = (float*)(ws + 262144);        //  4,194,304 B [n][co64][px]
    // reuse dead mid region after hgemm:
    u64*   iomask = (u64*)  (ws + 9437184);       // 18,048,000 B  [n][w][i]

    // host-computed anchor base (f64 math identical to the former device path)
    AnchBase ab;
    for (int a = 0; a < 9; ++a) {
        int ri = a / 3, si = a - ri * 3;
        double s = (double)(8 << si);
        double rr = (ri == 0) ? 0.5 : ((ri == 1) ? 1.0 : 2.0);
        double hh = 16.0 * s * sqrt(rr);
        double wd = 16.0 * s * sqrt(1.0 / rr);
        ab.v[a * 4 + 0] = (float)(8.0 - hh * 0.5);
        ab.v[a * 4 + 1] = (float)(8.0 - wd * 0.5);
        ab.v[a * 4 + 2] = (float)(8.0 + hh * 0.5);
        ab.v[a * 4 + 3] = (float)(8.0 + wd * 0.5);
    }

    k_prep_x<<<dim3(8, 64, 4), 256, 0, stream>>>(x, xh, xl);
    k_prep_w<<<1024, 256, 0, stream>>>(W1, Wh2, Wl2);
    k_conv_mfma<<<dim3(8, 64, 4), 256, 0, stream>>>(xh, xl, Wh2, Wl2, b1, mid);
    k_htrans<<<128, 256, 0, stream>>>(Ws, Wl, Wt2);
    k_hgemm<<<dim3(64, 4), 256, 0, stream>>>(mid, Wt2, sraw);
    k_decode<<<64, 256, 0, stream>>>(sraw, bs, bl, ih, iw, out, boxes, key, ab);
    k_misc<<<144, 256, 0, stream>>>(out, ab);
    k_selsort<<<4, 1024, 0, stream>>>(key, boxes, boxesS, nval);
    k_iou<<<dim3(NWORD, NWORD, NIMG), 64, 0, stream>>>(boxesS, iomask);
    k_nms3<<<NIMG, 64, 0, stream>>>(iomask, nval, boxesS, out + OFF2);
}

// Round 14
// 737.083 us; speedup vs baseline: 1.3711x; 1.3711x over previous
//
#include <hip/hip_runtime.h>
#include <math.h>

#define HH 64
#define WW 64
#define NIMG 4
#define CIN 512
#define AA 9
#define HWA (HH*WW*AA)          // 36864
#define PRE_NMS 6000
#define POST_NMS 300
#define NEGV (-1e10f)
#define NEGK 0xD01502F9u        // descending-order key of -1e10f
#define NWORD 94                // ceil(6000/64)

#define OFF1 589824             // rpn_scores
#define OFF2 884736             // rois
#define OFF3 889536             // roi_indices
#define OFF4 890736             // anchors

typedef unsigned int u32;
typedef unsigned long long u64;
typedef _Float16 f16;
typedef _Float16 half8 __attribute__((ext_vector_type(8)));
typedef float f32x4 __attribute__((ext_vector_type(4)));

struct AnchBase { float v[36]; };   // host-computed f64->f32 anchor base (4 per a)

__device__ __forceinline__ void gload_lds16(const void* g, void* l)
{
    __builtin_amdgcn_global_load_lds((const __attribute__((address_space(1))) void*)g,
                                     (__attribute__((address_space(3))) void*)l,
                                     16, 0, 0);
}

// ---------------- prep: x[n][ci][y][xc] f32 -> x_t[n][y][xc][ci] fp16 hi/lo ----------
__global__ __launch_bounds__(256) void k_prep_x(const float* __restrict__ x,
                                                f16* __restrict__ xh,
                                                f16* __restrict__ xl)
{
    __shared__ float tile[64][65];
    int ci0 = blockIdx.x * 64, y = blockIdx.y, n = blockIdx.z;
    int t = threadIdx.x;
    #pragma unroll
    for (int l = 0; l < 16; ++l) {
        int idx = l * 256 + t;
        int cc = idx >> 6, xc = idx & 63;
        tile[cc][xc] = x[((size_t)(n * CIN + ci0 + cc) * HH + y) * WW + xc];
    }
    __syncthreads();
    #pragma unroll
    for (int l = 0; l < 16; ++l) {
        int idx = l * 256 + t;
        int xc = idx >> 6, cc = idx & 63;
        float v = tile[cc][xc];
        f16 hi = (f16)v;
        f16 lo = (f16)(v - (float)hi);
        size_t o = ((size_t)(n * 64 + y) * 64 + xc) * 512 + ci0 + cc;
        xh[o] = hi; xl[o] = lo;
    }
}

// ---------------- prep: W1[co][ci][tap] f32 -> W2[tap][co][ci] fp16 hi/lo ----------
__global__ __launch_bounds__(256) void k_prep_w(const float* __restrict__ W1,
                                                f16* __restrict__ wh,
                                                f16* __restrict__ wl)
{
    int idx = blockIdx.x * 256 + threadIdx.x;   // 512*512
    int co = idx >> 9, ci = idx & 511;
    #pragma unroll
    for (int tap = 0; tap < 9; ++tap) {
        float v = W1[(size_t)idx * 9 + tap];
        f16 hi = (f16)v;
        f16 lo = (f16)(v - (float)hi);
        size_t o = ((size_t)tap * 512 + co) * 512 + ci;
        wh[o] = hi; wl[o] = lo;
    }
}

// ---------------- conv3x3 via MFMA fp16x3 implicit GEMM (R7/R12 version: 318us) -----
// Padded-column LDS [2][4][66][32] (cols 0,65 = zero pads): no oob cndmask in loadB.
__global__ __launch_bounds__(256, 4) void k_conv_mfma(const f16* __restrict__ xh,
                                                      const f16* __restrict__ xl,
                                                      const f16* __restrict__ wh,
                                                      const f16* __restrict__ wl,
                                                      const float* __restrict__ bias,
                                                      float* __restrict__ mid)
{
    __shared__ f16 sX[2][4][66][32];   // [plane][row y0-1..y0+2][col 0..65][ci] = 33792 B
    const int t = threadIdx.x;
    const int lid = blockIdx.x + 8 * (blockIdx.y + 32 * blockIdx.z);   // launched id
    const int logical = (lid & 7) * 128 + (lid >> 3);                  // bijective
    const int co0 = (logical & 7) * 64;
    const int g = logical >> 3;        // 0..127 = yb + 32*n
    const int yb = g & 31, n = g >> 5;
    const int y0 = yb * 2;
    const int wv = t >> 6, lane = t & 63;
    const int q = lane >> 4, li = lane & 15;
    const int mh = wv & 1;             // co half (32 co)
    const int xhp = wv >> 1;           // px half (32 px)

    // u32 strides: plane 4224, row 1056, col 16
    {   // zero pad columns (cols 0 and 65) of all 8 plane-rows: 256 u32 total
        int pr = t >> 5, j = t & 31;
        int col = (j < 16) ? 0 : 65, e = j & 15;
        u32* p = (u32*)&sX[0][0][0][0];
        p[(pr >> 2) * 4224 + (pr & 3) * 1056 + col * 16 + e] = 0;
    }
    if (yb == 0 || yb == 31) {         // zero full vertical-halo row (both planes)
        int r = (yb == 0) ? 0 : 3;
        u32* p = (u32*)&sX[0][0][0][0];
        #pragma unroll
        for (int l = 0; l < 9; ++l) {
            int idx = l * 256 + t;     // 0..2111 used
            if (idx < 2112) {
                int plane = (idx >= 1056) ? 1 : 0;
                int rr = idx - plane * 1056;
                p[plane * 4224 + r * 1056 + rr] = 0;
            }
        }
    }

    f32x4 acc[2][2][2];   // [mt][xn][yy]
    #pragma unroll
    for (int mt = 0; mt < 2; ++mt)
        #pragma unroll
        for (int xn = 0; xn < 2; ++xn)
            #pragma unroll
            for (int yy = 0; yy < 2; ++yy)
                acc[mt][xn][yy] = (f32x4){0.f, 0.f, 0.f, 0.f};

    // staging: 32 wave-insts x 1 KB; LDS col g+1 <- global col g, slot s_l receives
    // global ci-slot s_l ^ ((g>>1)&3) via pre-swizzled global source address.
    auto prefetch = [&](int ci0) {
        #pragma unroll
        for (int m = 0; m < 8; ++m) {
            int k2 = wv * 8 + m;               // 0..31, wave-uniform
            int plane = k2 >> 4;
            int row = (k2 >> 2) & 3;
            int gy = y0 - 1 + row;
            if ((unsigned)gy < 64u) {
                int col = ((k2 & 3) << 4) + (lane >> 2);
                int s = (lane & 3) ^ ((lane >> 3) & 3);   // pre-swizzled global slot
                const f16* src = (plane ? xl : xh) +
                    (((size_t)(n * 64 + gy) * 64 + col) * 512 + ci0 + s * 8);
                f16* dst = &sX[0][0][0][0] + (size_t)plane * 8448 + row * 2112
                           + (1 + (k2 & 3) * 16) * 32 + lane * 8;
                gload_lds16(src, dst);
            }
        }
    };

    const size_t wb0 = (size_t)(co0 + mh * 32 + li) * 512 + q * 8;
    const f16* pWh = wh + wb0;
    const f16* pWl = wl + wb0;
    half8 wa[2][2], wn[2][2];
    auto loadW = [&](half8 (&w)[2][2], int ci0, int tap) {
        #pragma unroll
        for (int mt = 0; mt < 2; ++mt) {
            size_t off = (size_t)tap * 262144 + (size_t)mt * 8192 + ci0;
            w[0][mt] = *(const half8*)(pWh + off);
            w[1][mt] = *(const half8*)(pWl + off);
        }
    };

    // loop-invariant B-read pointers: LDS col lc = xc + kx (0..65); global g = lc-1.
    const f16* pB[2][3];
    #pragma unroll
    for (int xn = 0; xn < 2; ++xn)
        #pragma unroll
        for (int kx = 0; kx < 3; ++kx) {
            int lc = xhp * 32 + xn * 16 + li + kx;
            int qe = q ^ (((lc - 1) >> 1) & 3);
            pB[xn][kx] = &sX[0][0][0][0] + lc * 32 + qe * 8;
        }

    auto loadB = [&](half8 (&Bf)[2][2][2], int tap) {
        const int ky = tap / 3, kx = tap - ky * 3;
        #pragma unroll
        for (int xn = 0; xn < 2; ++xn) {
            const f16* pb = pB[xn][kx];
            #pragma unroll
            for (int yy = 0; yy < 2; ++yy) {
                const f16* ph = pb + (yy + ky) * 2112;   // row stride 66*32 f16
                Bf[0][xn][yy] = *(const half8*)ph;
                Bf[1][xn][yy] = *(const half8*)(ph + 8448);  // plane stride f16
            }
        }
    };

    prefetch(0);
    loadW(wa, 0, 0);

    for (int chunk = 0; chunk < 16; ++chunk) {
        const int ci0 = chunk * 32;
        __syncthreads();

        half8 B0[2][2][2], Bn[2][2][2];
        loadB(B0, 0);

        #pragma unroll
        for (int tap = 0; tap < 9; ++tap) {
            if (tap < 8) {
                loadW(wn, ci0, tap + 1);
                loadB(Bn, tap + 1);
            }
            #pragma unroll
            for (int mt = 0; mt < 2; ++mt)
                #pragma unroll
                for (int xn = 0; xn < 2; ++xn)
                    #pragma unroll
                    for (int yy = 0; yy < 2; ++yy)
                        acc[mt][xn][yy] = __builtin_amdgcn_mfma_f32_16x16x32_f16(wa[0][mt], B0[0][xn][yy], acc[mt][xn][yy], 0, 0, 0);
            #pragma unroll
            for (int mt = 0; mt < 2; ++mt)
                #pragma unroll
                for (int xn = 0; xn < 2; ++xn)
                    #pragma unroll
                    for (int yy = 0; yy < 2; ++yy)
                        acc[mt][xn][yy] = __builtin_amdgcn_mfma_f32_16x16x32_f16(wa[0][mt], B0[1][xn][yy], acc[mt][xn][yy], 0, 0, 0);
            #pragma unroll
            for (int mt = 0; mt < 2; ++mt)
                #pragma unroll
                for (int xn = 0; xn < 2; ++xn)
                    #pragma unroll
                    for (int yy = 0; yy < 2; ++yy)
                        acc[mt][xn][yy] = __builtin_amdgcn_mfma_f32_16x16x32_f16(wa[1][mt], B0[0][xn][yy], acc[mt][xn][yy], 0, 0, 0);

            if (tap < 8) {
                #pragma unroll
                for (int pl = 0; pl < 2; ++pl)
                    #pragma unroll
                    for (int mt = 0; mt < 2; ++mt) wa[pl][mt] = wn[pl][mt];
                #pragma unroll
                for (int pl = 0; pl < 2; ++pl)
                    #pragma unroll
                    for (int xn = 0; xn < 2; ++xn)
                        #pragma unroll
                        for (int yy = 0; yy < 2; ++yy) B0[pl][xn][yy] = Bn[pl][xn][yy];
            }
        }

        if (chunk + 1 < 16) {
            __syncthreads();
            prefetch(ci0 + 32);
            loadW(wa, ci0 + 32, 0);
        }
    }

    #pragma unroll
    for (int mt = 0; mt < 2; ++mt) {
        #pragma unroll
        for (int r = 0; r < 4; ++r) {
            int co = co0 + mh * 32 + mt * 16 + q * 4 + r;
            float bv = bias[co];
            #pragma unroll
            for (int xn = 0; xn < 2; ++xn) {
                int xc = xhp * 32 + xn * 16 + li;
                #pragma unroll
                for (int yy = 0; yy < 2; ++yy) {
                    float v = acc[mt][xn][yy][r] + bv;
                    mid[((size_t)(n * 512 + co) * HH + y0 + yy) * WW + xc] = v > 0.f ? v : 0.f;
                }
            }
        }
    }
}

// ---------------- head weights -> [ci][co] (co: 0..17 score, 18..53 loc, pad 64) ----
__global__ __launch_bounds__(256) void k_htrans(const float* __restrict__ Ws,
                                                const float* __restrict__ Wl,
                                                float* __restrict__ Wt2)
{
    int i = blockIdx.x * 256 + threadIdx.x;   // 512*64
    if (i >= 512 * 64) return;
    int ci = i >> 6, co = i & 63;
    float v = 0.f;
    if (co < 18) v = Ws[co * 512 + ci];
    else if (co < 54) v = Wl[(co - 18) * 512 + ci];
    Wt2[i] = v;
}

// ---------------- 1x1 heads as GEMM: sraw[n][co64][px4096] ----------------
__global__ __launch_bounds__(256) void k_hgemm(const float* __restrict__ mid,
                                               const float* __restrict__ Wt2,
                                               float* __restrict__ sraw)
{
    __shared__ float sM[32][64];   // [ci][px]
    __shared__ float sW2[32][64];  // [ci][co]
    const int t = threadIdx.x;
    const int px0 = blockIdx.x * 64, n = blockIdx.y;
    const int tx = t & 15, ty = t >> 4;

    float acc[4][4];
    #pragma unroll
    for (int c = 0; c < 4; ++c)
        #pragma unroll
        for (int j = 0; j < 4; ++j) acc[c][j] = 0.f;

    for (int ci0 = 0; ci0 < 512; ci0 += 32) {
        __syncthreads();
        #pragma unroll
        for (int l = 0; l < 8; ++l) {
            int i = l * 256 + t;
            int ci = i >> 6, px = i & 63;
            sM[ci][px] = mid[((size_t)n * 512 + ci0 + ci) * 4096 + px0 + px];
            sW2[ci][px] = Wt2[(size_t)(ci0 + ci) * 64 + px];
        }
        __syncthreads();
        #pragma unroll
        for (int ci = 0; ci < 32; ++ci) {
            float mv[4], wv[4];
            #pragma unroll
            for (int j = 0; j < 4; ++j) mv[j] = sM[ci][tx * 4 + j];
            #pragma unroll
            for (int c = 0; c < 4; ++c) wv[c] = sW2[ci][ty * 4 + c];
            #pragma unroll
            for (int c = 0; c < 4; ++c)
                #pragma unroll
                for (int j = 0; j < 4; ++j) acc[c][j] += wv[c] * mv[j];
        }
    }
    #pragma unroll
    for (int c = 0; c < 4; ++c) {
        float4 v = make_float4(acc[c][0], acc[c][1], acc[c][2], acc[c][3]);
        *(float4*)&sraw[((size_t)n * 64 + ty * 4 + c) * 4096 + px0 + tx * 4] = v;
    }
}

// ---------------- decode: softmax, loc2bbox, clip, keys, head outputs ----------------
__global__ __launch_bounds__(256) void k_decode(const float* __restrict__ sraw,
                                                const float* __restrict__ bsc,
                                                const float* __restrict__ blc,
                                                const int* __restrict__ ph,
                                                const int* __restrict__ pw,
                                                float* __restrict__ out,
                                                float* __restrict__ boxes,
                                                u32* __restrict__ key,
                                                AnchBase ab)
{
    int p = blockIdx.x * 256 + threadIdx.x;   // 0..16383
    int n = p >> 12, pi = p & 4095;
    int y = pi >> 6, xq = pi & 63;

    const float* S = sraw + (size_t)n * 64 * 4096 + pi;
    float* o0 = out + (size_t)n * 147456;
    float* o1 = out + OFF1 + (size_t)n * 73728;
    float IHf = (float)(*ph), IWf = (float)(*pw);

    #pragma unroll
    for (int a = 0; a < 9; ++a) {
        float s0 = S[(size_t)(2 * a) * 4096] + bsc[2 * a];
        float s1 = S[(size_t)(2 * a + 1) * 4096] + bsc[2 * a + 1];
        float dy = S[(size_t)(18 + 4 * a) * 4096] + blc[4 * a];
        float dx = S[(size_t)(19 + 4 * a) * 4096] + blc[4 * a + 1];
        float dh = S[(size_t)(20 + 4 * a) * 4096] + blc[4 * a + 2];
        float dw = S[(size_t)(21 + 4 * a) * 4096] + blc[4 * a + 3];

        o1[(pi * 9 + a) * 2 + 0] = s0;
        o1[(pi * 9 + a) * 2 + 1] = s1;
        o0[(pi * 9 + a) * 4 + 0] = dy;
        o0[(pi * 9 + a) * 4 + 1] = dx;
        o0[(pi * 9 + a) * 4 + 2] = dh;
        o0[(pi * 9 + a) * 4 + 3] = dw;

        // softmax fg (max-subtracted like jax.nn.softmax)
        float mm = fmaxf(s0, s1);
        float e0 = expf(s0 - mm), e1 = expf(s1 - mm);
        float fg = e1 / (e0 + e1);

        // anchor base from host-computed table (bit-identical to f64 path)
        float a0 = ab.v[4 * a + 0] + (float)(y * 16);
        float a1 = ab.v[4 * a + 1] + (float)(xq * 16);
        float a2 = ab.v[4 * a + 2] + (float)(y * 16);
        float a3 = ab.v[4 * a + 3] + (float)(xq * 16);

        // loc2bbox
        float h = a2 - a0, w = a3 - a1;
        float cy = a0 + 0.5f * h, cx = a1 + 0.5f * w;
        float ncy = dy * h + cy, ncx = dx * w + cx;
        float nh = expf(dh) * h, nw = expf(dw) * w;
        float b0 = fminf(fmaxf(ncy - 0.5f * nh, 0.f), IHf);
        float b1 = fminf(fmaxf(ncx - 0.5f * nw, 0.f), IWf);
        float b2 = fminf(fmaxf(ncy + 0.5f * nh, 0.f), IHf);
        float b3 = fminf(fmaxf(ncx + 0.5f * nw, 0.f), IWf);

        bool ok = (b2 - b0 >= 16.0f) && (b3 - b1 >= 16.0f);
        float sc = ok ? fg : NEGV;

        int gi = n * HWA + pi * 9 + a;
        ((float4*)boxes)[gi] = make_float4(b0, b1, b2, b3);
        u32 u = __float_as_uint(sc);
        u32 kasc = (u & 0x80000000u) ? ~u : (u | 0x80000000u);
        key[gi] = ~kasc;   // ascending key == descending score
    }
}

// ---------------- anchors out + roi_indices + zero rois ----------------
__global__ void k_misc(float* __restrict__ out, AnchBase ab)
{
    int i = blockIdx.x * 256 + threadIdx.x;
    if (i < 4800) out[OFF2 + i] = 0.f;
    if (i < 1200) out[OFF3 + i] = (float)(i / 300);
    if (i < HWA) {
        int pi = i / 9, a = i - pi * 9;
        int y = pi >> 6, xq = pi & 63;
        out[OFF4 + i * 4 + 0] = ab.v[4 * a + 0] + (float)(y * 16);
        out[OFF4 + i * 4 + 1] = ab.v[4 * a + 1] + (float)(xq * 16);
        out[OFF4 + i * 4 + 2] = ab.v[4 * a + 2] + (float)(y * 16);
        out[OFF4 + i * 4 + 3] = ab.v[4 * a + 3] + (float)(xq * 16);
    }
}

// ---------------- fused select+sort: radix rank-6000 -> PHI-swizzled bitonic --------
// R14 (single change vs R12): bitonic uses PHI index swizzle + register-local j<=4
// stages (91 -> 68 barrier stages, ~1/3 less LDS traffic; PHI spreads each thread's
// 64B-contiguous block across 8 banks instead of 2). Verified-correct construction
// from R4's passing run; compact scatters to sK[PHI(p)], extraction reads sK[PHI(i)].
__device__ __forceinline__ int PHI(int i) { return i ^ (((i >> 3) & 7) << 1); }
__device__ __forceinline__ void cx(u64& a, u64& b, bool up)
{
    bool sw = up ? (a > b) : (a < b);
    u64 x = a, y = b;
    a = sw ? y : x;
    b = sw ? x : y;
}

__global__ __launch_bounds__(1024) void k_selsort(const u32* __restrict__ key,
                                                  const float* __restrict__ boxes,
                                                  float* __restrict__ boxesS,
                                                  int* __restrict__ nvalid)
{
    __shared__ u64 sK[8192];   // 64 KiB
    __shared__ int hist[256];
    __shared__ u32 sPref;
    __shared__ int sR;
    __shared__ int cLess, cEq, cVal;
    int n = blockIdx.x, t = threadIdx.x;
    const u32* k0 = key + (size_t)n * HWA;

    u32 pref = 0, mask = 0;
    int R = PRE_NMS;
    for (int pass = 0; pass < 4; ++pass) {
        int shift = 24 - pass * 8;
        if (t < 256) hist[t] = 0;
        __syncthreads();
        for (int i = t; i < HWA; i += 1024) {
            u32 k = k0[i];
            if ((k & mask) == pref) atomicAdd(&hist[(k >> shift) & 255], 1);
        }
        __syncthreads();
        if (t == 0) {
            int cum = 0;
            for (int b = 0; b < 256; ++b) {
                int c = hist[b];
                if (cum + c >= R) { sPref = pref | ((u32)b << shift); sR = R - cum; break; }
                cum += c;
            }
        }
        __syncthreads();
        pref = sPref; R = sR; mask |= (0xFFu << shift);
        __syncthreads();
    }
    u32 T = pref;   // exact 6000th smallest key
    if (t == 0) { cLess = 0; cEq = 0; cVal = 0; }
    __syncthreads();
    for (int i = t; i < HWA; i += 1024) {
        u32 k = k0[i];
        if (k < NEGK) atomicAdd(&cVal, 1);
        if (k < T) {
            int p = atomicAdd(&cLess, 1);
            sK[PHI(p)] = ((u64)k << 32) | (u32)i;
        } else if (k == T) {
            int p = atomicAdd(&cEq, 1);
            if (p < R) sK[PHI(PRE_NMS - 1 - p)] = ((u64)k << 32) | (u32)i;
        }
    }
    for (int i = PRE_NMS + t; i < 8192; i += 1024) sK[PHI(i)] = ~0ull;
    __syncthreads();
    if (t == 0) nvalid[n] = cVal < PRE_NMS ? cVal : PRE_NMS;

    // bitonic sort of 8192: global stages j>=8 (PHI addressing), local j<=4 in regs
    for (unsigned k = 2; k <= 8192; k <<= 1) {
        for (unsigned j = k >> 1; j >= 8; j >>= 1) {
            __syncthreads();
            #pragma unroll
            for (int v = 0; v < 8; ++v) {
                int i = v * 1024 + t;
                int ixj = i ^ (int)j;
                if (ixj > i) {
                    u64 a = sK[PHI(i)], b = sK[PHI(ixj)];
                    bool up = ((i & (int)k) == 0);
                    if (up ? (a > b) : (a < b)) { sK[PHI(i)] = b; sK[PHI(ixj)] = a; }
                }
            }
        }
        __syncthreads();
        {
            int base = t * 8;
            u64 r[8];
            #pragma unroll
            for (int e = 0; e < 8; ++e) r[e] = sK[PHI(base + e)];
            if (k >= 8) {
                bool up = ((base & (int)k) == 0);
                cx(r[0], r[4], up); cx(r[1], r[5], up); cx(r[2], r[6], up); cx(r[3], r[7], up);
                cx(r[0], r[2], up); cx(r[1], r[3], up); cx(r[4], r[6], up); cx(r[5], r[7], up);
                cx(r[0], r[1], up); cx(r[2], r[3], up); cx(r[4], r[5], up); cx(r[6], r[7], up);
            } else if (k == 4) {
                cx(r[0], r[2], true); cx(r[1], r[3], true); cx(r[4], r[6], false); cx(r[5], r[7], false);
                cx(r[0], r[1], true); cx(r[2], r[3], true); cx(r[4], r[5], false); cx(r[6], r[7], false);
            } else {   // k == 2
                cx(r[0], r[1], true); cx(r[2], r[3], false); cx(r[4], r[5], true); cx(r[6], r[7], false);
            }
            #pragma unroll
            for (int e = 0; e < 8; ++e) sK[PHI(base + e)] = r[e];
        }
        __syncthreads();
    }
    const float4* bsrc = (const float4*)boxes + (size_t)n * HWA;
    float4* bdst = (float4*)boxesS + (size_t)n * PRE_NMS;
    for (int i = t; i < PRE_NMS; i += 1024) {
        u32 idx = (u32)(sK[PHI(i)] & 0xFFFFFFFFu);
        bdst[i] = bsrc[idx];
    }
}

// ---------------- IoU suppression bitmask, WORD-MAJOR: mask[n][w][i] ----------------
__global__ __launch_bounds__(64) void k_iou(const float* __restrict__ boxesS,
                                            u64* __restrict__ mask)
{
    __shared__ float4 cb[64];
    int w = blockIdx.x, ic = blockIdx.y, n = blockIdx.z;
    if (w < ic) return;                       // strictly-lower triangle: unused
    int t = threadIdx.x;
    const float4* B = (const float4*)boxesS + (size_t)n * PRE_NMS;
    int jc = w * 64 + t;
    cb[t] = (jc < PRE_NMS) ? B[jc] : make_float4(0.f, 0.f, 0.f, 0.f);
    __syncthreads();
    int i = ic * 64 + t;
    if (i >= PRE_NMS) return;
    float4 bb = B[i];
    float area1 = (bb.z - bb.x) * (bb.w - bb.y);
    u64 m = 0;
    #pragma unroll 8
    for (int j = 0; j < 64; ++j) {
        float4 o = cb[j];
        float ty_ = fmaxf(bb.x, o.x), tx_ = fmaxf(bb.y, o.y);
        float by_ = fminf(bb.z, o.z), bx_ = fminf(bb.w, o.w);
        float inter = fmaxf(by_ - ty_, 0.f) * fmaxf(bx_ - tx_, 0.f);
        float area2 = (o.z - o.x) * (o.w - o.y);
        float iou = inter / (area1 + area2 - inter + 1e-9f);
        if (iou > 0.7f) m |= (1ull << j);
    }
    mask[((size_t)n * NWORD + w) * PRE_NMS + i] = m;   // contiguous per block
}

// ---------------- greedy bitmask NMS: chunk-resolved, word-major mask ---------------
__global__ __launch_bounds__(64) void k_nms3(const u64* __restrict__ mask,
                                             const int* __restrict__ nvalid,
                                             const float* __restrict__ boxesS,
                                             float* __restrict__ rois)
{
    __shared__ u64 diag[NWORD * 128];   // per chunk: 64 used + 64 overread slack
    int n = blockIdx.x, lane = threadIdx.x;
    int nv = nvalid[n];
    const u64* M = mask + (size_t)n * NWORD * PRE_NMS;   // [w][i]
    const float4* B = (const float4*)boxesS + (size_t)n * PRE_NMS;

    auto vmask = [&](int w) -> u64 {
        int lo = w * 64;
        if (nv >= lo + 64) return ~0ull;
        if (nv <= lo) return 0ull;
        return (1ull << (nv - lo)) - 1ull;
    };
    u64 c0 = vmask(lane);                                      // words 0..63
    u64 c1 = (lane < NWORD - 64) ? vmask(64 + lane) : 0ull;    // words 64..93

    for (int c = 0; c < NWORD; ++c) {
        const char* src = (const char*)(M + (size_t)c * PRE_NMS + c * 64) + lane * 16;
        gload_lds16(src, &diag[(size_t)c * 128]);
    }
    asm volatile("s_waitcnt vmcnt(0)" ::: "memory");
    __builtin_amdgcn_sched_barrier(0);

    const u64* Mw0 = M + (size_t)lane * PRE_NMS;
    const u64* Mw1 = (lane < NWORD - 64) ? (M + (size_t)(64 + lane) * PRE_NMS) : M;

    int cnt = 0;
    for (int c = 0; c < NWORD; ++c) {
        u64 w = (c < 64) ? __shfl(c0, c) : __shfl(c1, c - 64);   // uniform word
        if (w == 0) continue;

        u64 dl = diag[(size_t)c * 128 + lane];

        u64 selw = 0;
        u64 ww = w;
        while (ww && cnt < POST_NMS) {
            int j = __builtin_ctzll(ww);
            int sel = c * 64 + j;
            if (lane == 0) {
                float4 bb = B[sel];
                float* orow = rois + (size_t)(n * POST_NMS + cnt) * 4;
                orow[0] = bb.x; orow[1] = bb.y; orow[2] = bb.z; orow[3] = bb.w;
            }
            cnt++;
            selw |= 1ull << j;
            u64 dj = __shfl(dl, j);          // row sel's word c (self-bit set)
            ww &= ~dj;
            ww &= ~(1ull << j);
        }
        if (cnt >= POST_NMS) break;

        u64 s = selw;
        while (s) {
            int ids[8];
            u64 r0v[8], r1v[8];
            #pragma unroll
            for (int z = 0; z < 8; ++z) {
                int idz = -1;
                if (s) { int j = __builtin_ctzll(s); s &= s - 1; idz = c * 64 + j; }
                ids[z] = idz;
            }
            #pragma unroll
            for (int z = 0; z < 8; ++z) {
                if (ids[z] >= 0) {
                    r0v[z] = Mw0[ids[z]];
                    r1v[z] = (lane < NWORD - 64) ? Mw1[ids[z]] : 0ull;
                } else { r0v[z] = 0ull; r1v[z] = 0ull; }
            }
            #pragma unroll
            for (int z = 0; z < 8; ++z) { c0 &= ~r0v[z]; c1 &= ~r1v[z]; }
        }
    }
}

extern "C" void kernel_launch(void* const* d_in, const int* in_sizes, int n_in,
                              void* d_out, int out_size, void* d_ws, size_t ws_size,
                              hipStream_t stream)
{
    const float* x  = (const float*)d_in[0];
    const float* W1 = (const float*)d_in[1];
    const float* b1 = (const float*)d_in[2];
    const float* Ws = (const float*)d_in[3];
    const float* bs = (const float*)d_in[4];
    const float* Wl = (const float*)d_in[5];
    const float* bl = (const float*)d_in[6];
    const int* ih   = (const int*)d_in[7];
    const int* iw   = (const int*)d_in[8];
    float* out = (float*)d_out;
    char* ws = (char*)d_ws;

    // during conv:
    f16*   Wh2    = (f16*)  (ws);                 //  4,718,592 B (dead after conv)
    f16*   Wl2    = (f16*)  (ws + 4718592);       //  4,718,592 B (dead after conv)
    float* mid    = (float*)(ws + 9437184);       // 33,554,432 B (dead after hgemm)
    f16*   xh     = (f16*)  (ws + 42991616);      // 16,777,216 B (dead after conv)
    f16*   xl     = (f16*)  (ws + 59768832);      // 16,777,216 B (dead after conv)
    // after conv (reusing xh region at identical old offsets):
    float* boxes  = (float*)(ws + 42991616);      //  2,359,296 B
    u32*   key    = (u32*)  (ws + 45350912);      //    589,824 B
    float* boxesS = (float*)(ws + 46202880);      //    384,000 B
    int*   nval   = (int*)  (ws + 46586880);      //         16 B
    // reuse dead Wh2 region after conv:
    float* Wt2    = (float*)(ws);                 //    131,072 B [ci][co64]
    float* sraw   = (float*)(ws + 262144);        //  4,194,304 B [n][co64][px]
    // reuse dead mid region after hgemm:
    u64*   iomask = (u64*)  (ws + 9437184);       // 18,048,000 B  [n][w][i]

    // host-computed anchor base (f64 math identical to the former device path)
    AnchBase ab;
    for (int a = 0; a < 9; ++a) {
        int ri = a / 3, si = a - ri * 3;
        double s = (double)(8 << si);
        double rr = (ri == 0) ? 0.5 : ((ri == 1) ? 1.0 : 2.0);
        double hh = 16.0 * s * sqrt(rr);
        double wd = 16.0 * s * sqrt(1.0 / rr);
        ab.v[a * 4 + 0] = (float)(8.0 - hh * 0.5);
        ab.v[a * 4 + 1] = (float)(8.0 - wd * 0.5);
        ab.v[a * 4 + 2] = (float)(8.0 + hh * 0.5);
        ab.v[a * 4 + 3] = (float)(8.0 + wd * 0.5);
    }

    k_prep_x<<<dim3(8, 64, 4), 256, 0, stream>>>(x, xh, xl);
    k_prep_w<<<1024, 256, 0, stream>>>(W1, Wh2, Wl2);
    k_conv_mfma<<<dim3(8, 32, 4), 256, 0, stream>>>(xh, xl, Wh2, Wl2, b1, mid);
    k_htrans<<<128, 256, 0, stream>>>(Ws, Wl, Wt2);
    k_hgemm<<<dim3(64, 4), 256, 0, stream>>>(mid, Wt2, sraw);
    k_decode<<<64, 256, 0, stream>>>(sraw, bs, bl, ih, iw, out, boxes, key, ab);
    k_misc<<<144, 256, 0, stream>>>(out, ab);
    k_selsort<<<4, 1024, 0, stream>>>(key, boxes, boxesS, nval);
    k_iou<<<dim3(NWORD, NWORD, NIMG), 64, 0, stream>>>(boxesS, iomask);
    k_nms3<<<NIMG, 64, 0, stream>>>(iomask, nval, boxesS, out + OFF2);
}